// Round 3
// baseline (412.033 us; speedup 1.0000x reference)
//
#include <hip/hip_runtime.h>

#define NTOK 8192
#define DD 1024
#define HH 4096
#define EE 8
#define MAXBLK 72
#define NT1 16   // DD/64 K-tiles for gemm1
#define NT2 64   // HH/64 K-tiles for gemm2

typedef __attribute__((ext_vector_type(8))) short bf16x8;
typedef __attribute__((ext_vector_type(4))) float f32x4;

__device__ __forceinline__ unsigned short f2bf(float f) {
  unsigned u = __builtin_bit_cast(unsigned, f);
  u += 0x7fffu + ((u >> 16) & 1u);  // round-to-nearest-even
  return (unsigned short)(u >> 16);
}

union Pack8 {
  unsigned short u[8];
  uint4 v;
};

__device__ __forceinline__ void gload_lds16(const void* g, void* l) {
  __builtin_amdgcn_global_load_lds(
      (const __attribute__((address_space(1))) unsigned int*)g,
      (__attribute__((address_space(3))) unsigned int*)l, 16, 0, 0);
}

// ---------------- Router (fused x -> bf16 convert) ----------------
__global__ __launch_bounds__(256) void k_router(
    const float* __restrict__ x, const float* __restrict__ Wr,
    const float* __restrict__ br, float* __restrict__ probs,
    float* __restrict__ idxf, int* __restrict__ idxi,
    unsigned short* __restrict__ xb) {
  const int lane = threadIdx.x & 63;
  const int token = blockIdx.x * 4 + (threadIdx.x >> 6);
  const float* xr = x + (size_t)token * DD;

  float acc[EE];
#pragma unroll
  for (int e = 0; e < EE; ++e) acc[e] = 0.f;

#pragma unroll
  for (int i = 0; i < 4; ++i) {
    const int d0 = i * 256 + lane * 4;
    const float4 xv = *reinterpret_cast<const float4*>(xr + d0);
    // fused bf16 convert + store
    union { unsigned short u[4]; uint2 v; } pk;
    pk.u[0] = f2bf(xv.x); pk.u[1] = f2bf(xv.y);
    pk.u[2] = f2bf(xv.z); pk.u[3] = f2bf(xv.w);
    *reinterpret_cast<uint2*>(xb + (size_t)token * DD + d0) = pk.v;
    const float xs[4] = {xv.x, xv.y, xv.z, xv.w};
#pragma unroll
    for (int j = 0; j < 4; ++j) {
      const float xd = xs[j];
      const float4 w0 = *reinterpret_cast<const float4*>(Wr + (size_t)(d0 + j) * EE);
      const float4 w1 = *reinterpret_cast<const float4*>(Wr + (size_t)(d0 + j) * EE + 4);
      acc[0] += xd * w0.x; acc[1] += xd * w0.y; acc[2] += xd * w0.z; acc[3] += xd * w0.w;
      acc[4] += xd * w1.x; acc[5] += xd * w1.y; acc[6] += xd * w1.z; acc[7] += xd * w1.w;
    }
  }
#pragma unroll
  for (int s = 32; s > 0; s >>= 1) {
#pragma unroll
    for (int e = 0; e < EE; ++e) acc[e] += __shfl_xor(acc[e], s, 64);
  }

  float lg[EE];
#pragma unroll
  for (int e = 0; e < EE; ++e) lg[e] = acc[e] + br[e];

  int best = 0;
  float bv = lg[0];
#pragma unroll
  for (int e = 1; e < EE; ++e) {
    if (lg[e] > bv) { bv = lg[e]; best = e; }  // strict > = numpy first-max
  }
  float p[EE], s = 0.f;
#pragma unroll
  for (int e = 0; e < EE; ++e) { p[e] = expf(lg[e] - bv); s += p[e]; }
  const float inv = 1.f / s;

  if (lane == 0) {
#pragma unroll
    for (int e = 0; e < EE; ++e) probs[(size_t)token * EE + e] = p[e] * inv;
    idxf[token] = (float)best;
    idxi[token] = best;
  }
}

// ------------- Stable compaction + block table -------------
__global__ __launch_bounds__(512) void k_compact(const int* __restrict__ idxi,
                                                 int* __restrict__ cnt,
                                                 int* __restrict__ off,
                                                 int* __restrict__ sorted,
                                                 int* __restrict__ meta) {
  __shared__ int sidx[NTOK];
  __shared__ int scnt[EE], soff[EE];
  const int tid = threadIdx.x;
  for (int i = tid; i < NTOK; i += 512) sidx[i] = idxi[i];
  __syncthreads();
  const int w = tid >> 6, lane = tid & 63;
  if (w < EE) {
    int c = 0;
    for (int i = 0; i < NTOK / 64; ++i) {
      unsigned long long m = __ballot(sidx[i * 64 + lane] == w);
      c += __popcll(m);
    }
    if (lane == 0) scnt[w] = c;
  }
  __syncthreads();
  if (tid == 0) {
    int s = 0;
    for (int e = 0; e < EE; ++e) { soff[e] = s; s += scnt[e]; }
    int nb = 0;
    for (int e = 0; e < EE; ++e) {
      const int nmb = (scnt[e] + 127) >> 7;
      for (int m = 0; m < nmb; ++m) {
        meta[16 + nb] = e;
        meta[96 + nb] = m << 7;
        ++nb;
      }
    }
    meta[0] = nb;
  }
  __syncthreads();
  if (w < EE) {
    int base = soff[w];
    const unsigned long long ltmask = (1ull << lane) - 1ull;
    for (int i = 0; i < NTOK / 64; ++i) {
      const int tok = i * 64 + lane;
      const bool f = (sidx[tok] == w);
      unsigned long long m = __ballot(f);
      if (f) {
        int r = __popcll(m & ltmask);
        sorted[base + r] = tok;
      }
      base += __popcll(m);
    }
    if (lane == 0) { cnt[w] = scnt[w]; off[w] = soff[w]; }
  }
}

// ---------------- transpose+convert 64x64: in [E][R][C] f32 -> out [E][C][R] bf16 ----------------
__global__ __launch_bounds__(256) void k_trcvt64(const float* __restrict__ in,
                                                 unsigned short* __restrict__ outp,
                                                 int R, int C) {
  const int e = blockIdx.z;
  const int r0 = blockIdx.y * 64, c0 = blockIdx.x * 64;
  const float* src = in + (size_t)e * R * C + (size_t)r0 * C + c0;
  unsigned short* dst = outp + (size_t)e * R * C + (size_t)c0 * R + r0;
  __shared__ unsigned short t[64 * 66];
  const int tid = threadIdx.x;
#pragma unroll
  for (int it = 0; it < 4; ++it) {
    const int r = it * 16 + (tid >> 4), c4 = (tid & 15) * 4;
    const float4 v = *reinterpret_cast<const float4*>(src + (size_t)r * C + c4);
    t[r * 66 + c4 + 0] = f2bf(v.x);
    t[r * 66 + c4 + 1] = f2bf(v.y);
    t[r * 66 + c4 + 2] = f2bf(v.z);
    t[r * 66 + c4 + 3] = f2bf(v.w);
  }
  __syncthreads();
#pragma unroll
  for (int it = 0; it < 2; ++it) {
    const int cc = it * 32 + (tid >> 3), r8 = (tid & 7) * 8;
    Pack8 p;
#pragma unroll
    for (int j = 0; j < 8; ++j) p.u[j] = t[(r8 + j) * 66 + cc];
    *reinterpret_cast<uint4*>(dst + (size_t)cc * R + r8) = p.v;
  }
}

// ---------------- GEMM1: h = relu(xb_sel @ W1t^T + b1) -> bf16 (dbuf pipelined) ----------------
__global__ __launch_bounds__(256) void k_gemm1n(
    const unsigned short* __restrict__ xb, const unsigned short* __restrict__ W1t,
    const float* __restrict__ b1, const int* __restrict__ meta,
    const int* __restrict__ cnt, const int* __restrict__ off,
    const int* __restrict__ sorted, unsigned short* __restrict__ h) {
  const int bid = blockIdx.x;
  if (bid >= meta[0]) return;
  const int e = meta[16 + bid];
  const int m0 = meta[96 + bid];
  const int c = cnt[e], base = off[e];
  const int n0 = blockIdx.y * 128;

  __shared__ __align__(16) unsigned short Al[2][128 * 64];
  __shared__ __align__(16) unsigned short Bl[2][128 * 64];

  const int tid = threadIdx.x, l = tid & 63, w = tid >> 6;

  const unsigned short* aptr[4];
  const unsigned short* bptr[4];
  int soff4[4];
#pragma unroll
  for (int i = 0; i < 4; ++i) {
    const int r = i * 32 + w * 8 + (l >> 3);
    const int swz = ((l & 7) ^ (r & 7)) * 8;  // pre-swizzled global source
    int ar = m0 + r; if (ar >= c) ar = c - 1;
    const int tok = sorted[base + ar];
    aptr[i] = xb + (size_t)tok * DD + swz;
    bptr[i] = W1t + ((size_t)e * HH + n0 + r) * DD + swz;
    soff4[i] = r * 64 + (l & 7) * 8;
  }

  const int lr = l & 15, lg = l >> 4;
  const int wr = w >> 1, wc = w & 1;
  int aoff[4], boff[4], asw[4], bsw[4];
#pragma unroll
  for (int m = 0; m < 4; ++m) {
    int row = wr * 64 + m * 16 + lr;
    aoff[m] = row * 64; asw[m] = row & 7;
    row = wc * 64 + m * 16 + lr;
    boff[m] = row * 64; bsw[m] = row & 7;
  }

  f32x4 acc[4][4];
#pragma unroll
  for (int m = 0; m < 4; ++m)
#pragma unroll
    for (int n = 0; n < 4; ++n) acc[m][n] = {0.f, 0.f, 0.f, 0.f};

  // prologue: stage tile 0 into buf 0
#pragma unroll
  for (int i = 0; i < 4; ++i) gload_lds16(aptr[i], &Al[0][soff4[i]]);
#pragma unroll
  for (int i = 0; i < 4; ++i) gload_lds16(bptr[i], &Bl[0][soff4[i]]);

  int cur = 0;
#pragma unroll 1
  for (int t = 0; t < NT1 - 1; ++t) {
    const int kn = (t + 1) * 64;
#pragma unroll
    for (int i = 0; i < 4; ++i) gload_lds16(aptr[i] + kn, &Al[cur ^ 1][soff4[i]]);
    asm volatile("s_waitcnt vmcnt(4)" ::: "memory");  // current tile's 8 done
    __builtin_amdgcn_s_barrier();
    {
      bf16x8 af[4], bv[4];
#pragma unroll
      for (int m = 0; m < 4; ++m)
        af[m] = *reinterpret_cast<const bf16x8*>(&Al[cur][aoff[m] + ((lg ^ asw[m]) * 8)]);
#pragma unroll
      for (int n = 0; n < 4; ++n)
        bv[n] = *reinterpret_cast<const bf16x8*>(&Bl[cur][boff[n] + ((lg ^ bsw[n]) * 8)]);
#pragma unroll
      for (int m = 0; m < 4; ++m)
#pragma unroll
        for (int n = 0; n < 4; ++n)
          acc[m][n] = __builtin_amdgcn_mfma_f32_16x16x32_bf16(af[m], bv[n], acc[m][n], 0, 0, 0);
    }
#pragma unroll
    for (int i = 0; i < 4; ++i) gload_lds16(bptr[i] + kn, &Bl[cur ^ 1][soff4[i]]);
    {
      bf16x8 af[4], bv[4];
#pragma unroll
      for (int m = 0; m < 4; ++m)
        af[m] = *reinterpret_cast<const bf16x8*>(&Al[cur][aoff[m] + (((4 + lg) ^ asw[m]) * 8)]);
#pragma unroll
      for (int n = 0; n < 4; ++n)
        bv[n] = *reinterpret_cast<const bf16x8*>(&Bl[cur][boff[n] + (((4 + lg) ^ bsw[n]) * 8)]);
#pragma unroll
      for (int m = 0; m < 4; ++m)
#pragma unroll
        for (int n = 0; n < 4; ++n)
          acc[m][n] = __builtin_amdgcn_mfma_f32_16x16x32_bf16(af[m], bv[n], acc[m][n], 0, 0, 0);
    }
    __builtin_amdgcn_s_barrier();
    cur ^= 1;
  }
  // final tile
  asm volatile("s_waitcnt vmcnt(0)" ::: "memory");
  __builtin_amdgcn_s_barrier();
#pragma unroll
  for (int ks = 0; ks < 2; ++ks) {
    bf16x8 af[4], bv[4];
#pragma unroll
    for (int m = 0; m < 4; ++m)
      af[m] = *reinterpret_cast<const bf16x8*>(&Al[cur][aoff[m] + (((ks * 4 + lg) ^ asw[m]) * 8)]);
#pragma unroll
    for (int n = 0; n < 4; ++n)
      bv[n] = *reinterpret_cast<const bf16x8*>(&Bl[cur][boff[n] + (((ks * 4 + lg) ^ bsw[n]) * 8)]);
#pragma unroll
    for (int m = 0; m < 4; ++m)
#pragma unroll
      for (int n = 0; n < 4; ++n)
        acc[m][n] = __builtin_amdgcn_mfma_f32_16x16x32_bf16(af[m], bv[n], acc[m][n], 0, 0, 0);
  }

  const int valid = c - m0;
#pragma unroll
  for (int m = 0; m < 4; ++m) {
#pragma unroll
    for (int rr = 0; rr < 4; ++rr) {
      const int tr = wr * 64 + m * 16 + lg * 4 + rr;
      if (tr < valid) {
        const size_t row = (size_t)(base + m0 + tr);
#pragma unroll
        for (int n = 0; n < 4; ++n) {
          const int col = n0 + wc * 64 + n * 16 + lr;
          const float v = acc[m][n][rr] + b1[e * HH + col];
          h[row * HH + col] = f2bf(fmaxf(v, 0.f));
        }
      }
    }
  }
}

// ---------------- GEMM2: out[token] = h @ W2t^T + b2 (dbuf pipelined, scatter) ----------------
__global__ __launch_bounds__(256) void k_gemm2n(
    const unsigned short* __restrict__ h, const unsigned short* __restrict__ W2t,
    const float* __restrict__ b2, const int* __restrict__ meta,
    const int* __restrict__ cnt, const int* __restrict__ off,
    const int* __restrict__ sorted, float* __restrict__ out) {
  const int bid = blockIdx.x;
  if (bid >= meta[0]) return;
  const int e = meta[16 + bid];
  const int m0 = meta[96 + bid];
  const int c = cnt[e], base = off[e];
  const int n0 = blockIdx.y * 128;

  __shared__ __align__(16) unsigned short Al[2][128 * 64];
  __shared__ __align__(16) unsigned short Bl[2][128 * 64];

  const int tid = threadIdx.x, l = tid & 63, w = tid >> 6;

  const unsigned short* aptr[4];
  const unsigned short* bptr[4];
  int soff4[4];
#pragma unroll
  for (int i = 0; i < 4; ++i) {
    const int r = i * 32 + w * 8 + (l >> 3);
    const int swz = ((l & 7) ^ (r & 7)) * 8;
    int ar = m0 + r; if (ar >= c) ar = c - 1;
    aptr[i] = h + (size_t)(base + ar) * HH + swz;
    bptr[i] = W2t + ((size_t)e * DD + n0 + r) * HH + swz;
    soff4[i] = r * 64 + (l & 7) * 8;
  }

  const int lr = l & 15, lg = l >> 4;
  const int wr = w >> 1, wc = w & 1;
  int aoff[4], boff[4], asw[4], bsw[4];
#pragma unroll
  for (int m = 0; m < 4; ++m) {
    int row = wr * 64 + m * 16 + lr;
    aoff[m] = row * 64; asw[m] = row & 7;
    row = wc * 64 + m * 16 + lr;
    boff[m] = row * 64; bsw[m] = row & 7;
  }

  f32x4 acc[4][4];
#pragma unroll
  for (int m = 0; m < 4; ++m)
#pragma unroll
    for (int n = 0; n < 4; ++n) acc[m][n] = {0.f, 0.f, 0.f, 0.f};

#pragma unroll
  for (int i = 0; i < 4; ++i) gload_lds16(aptr[i], &Al[0][soff4[i]]);
#pragma unroll
  for (int i = 0; i < 4; ++i) gload_lds16(bptr[i], &Bl[0][soff4[i]]);

  int cur = 0;
#pragma unroll 1
  for (int t = 0; t < NT2 - 1; ++t) {
    const int kn = (t + 1) * 64;
#pragma unroll
    for (int i = 0; i < 4; ++i) gload_lds16(aptr[i] + kn, &Al[cur ^ 1][soff4[i]]);
    asm volatile("s_waitcnt vmcnt(4)" ::: "memory");
    __builtin_amdgcn_s_barrier();
    {
      bf16x8 af[4], bv[4];
#pragma unroll
      for (int m = 0; m < 4; ++m)
        af[m] = *reinterpret_cast<const bf16x8*>(&Al[cur][aoff[m] + ((lg ^ asw[m]) * 8)]);
#pragma unroll
      for (int n = 0; n < 4; ++n)
        bv[n] = *reinterpret_cast<const bf16x8*>(&Bl[cur][boff[n] + ((lg ^ bsw[n]) * 8)]);
#pragma unroll
      for (int m = 0; m < 4; ++m)
#pragma unroll
        for (int n = 0; n < 4; ++n)
          acc[m][n] = __builtin_amdgcn_mfma_f32_16x16x32_bf16(af[m], bv[n], acc[m][n], 0, 0, 0);
    }
#pragma unroll
    for (int i = 0; i < 4; ++i) gload_lds16(bptr[i] + kn, &Bl[cur ^ 1][soff4[i]]);
    {
      bf16x8 af[4], bv[4];
#pragma unroll
      for (int m = 0; m < 4; ++m)
        af[m] = *reinterpret_cast<const bf16x8*>(&Al[cur][aoff[m] + (((4 + lg) ^ asw[m]) * 8)]);
#pragma unroll
      for (int n = 0; n < 4; ++n)
        bv[n] = *reinterpret_cast<const bf16x8*>(&Bl[cur][boff[n] + (((4 + lg) ^ bsw[n]) * 8)]);
#pragma unroll
      for (int m = 0; m < 4; ++m)
#pragma unroll
        for (int n = 0; n < 4; ++n)
          acc[m][n] = __builtin_amdgcn_mfma_f32_16x16x32_bf16(af[m], bv[n], acc[m][n], 0, 0, 0);
    }
    __builtin_amdgcn_s_barrier();
    cur ^= 1;
  }
  asm volatile("s_waitcnt vmcnt(0)" ::: "memory");
  __builtin_amdgcn_s_barrier();
#pragma unroll
  for (int ks = 0; ks < 2; ++ks) {
    bf16x8 af[4], bv[4];
#pragma unroll
    for (int m = 0; m < 4; ++m)
      af[m] = *reinterpret_cast<const bf16x8*>(&Al[cur][aoff[m] + (((ks * 4 + lg) ^ asw[m]) * 8)]);
#pragma unroll
    for (int n = 0; n < 4; ++n)
      bv[n] = *reinterpret_cast<const bf16x8*>(&Bl[cur][boff[n] + (((ks * 4 + lg) ^ bsw[n]) * 8)]);
#pragma unroll
    for (int m = 0; m < 4; ++m)
#pragma unroll
      for (int n = 0; n < 4; ++n)
        acc[m][n] = __builtin_amdgcn_mfma_f32_16x16x32_bf16(af[m], bv[n], acc[m][n], 0, 0, 0);
  }

  const int valid = c - m0;
#pragma unroll
  for (int m = 0; m < 4; ++m) {
#pragma unroll
    for (int rr = 0; rr < 4; ++rr) {
      const int tr = wr * 64 + m * 16 + lg * 4 + rr;
      if (tr < valid) {
        const int token = sorted[base + m0 + tr];
#pragma unroll
        for (int n = 0; n < 4; ++n) {
          const int col = n0 + wc * 64 + n * 16 + lr;
          out[(size_t)token * DD + col] = acc[m][n][rr] + b2[e * DD + col];
        }
      }
    }
  }
}

extern "C" void kernel_launch(void* const* d_in, const int* in_sizes, int n_in,
                              void* d_out, int out_size, void* d_ws, size_t ws_size,
                              hipStream_t stream) {
  const float* x  = (const float*)d_in[0];
  const float* Wr = (const float*)d_in[1];
  const float* br = (const float*)d_in[2];
  const float* W1 = (const float*)d_in[3];
  const float* b1 = (const float*)d_in[4];
  const float* W2 = (const float*)d_in[5];
  const float* b2 = (const float*)d_in[6];

  float* out   = (float*)d_out;
  float* probs = out + (size_t)NTOK * DD;
  float* idxf  = probs + (size_t)NTOK * EE;

  char* ws = (char*)d_ws;
  int* cnt    = (int*)(ws + 0);
  int* off    = (int*)(ws + 64);
  int* meta   = (int*)(ws + 128);      // [0]=nblk, [16..]=blk_e, [96..]=blk_m0
  int* idxi   = (int*)(ws + 1024);
  int* sorted = (int*)(ws + 33792);

  const size_t OFF_XB  = 66560;                                  // 16 MB
  const size_t OFF_W1T = OFF_XB + (size_t)NTOK * DD * 2;         // +64 MB
  const size_t OFF_H   = OFF_W1T + (size_t)EE * DD * HH * 2;     // +64 MB
  const size_t OFF_W2T = OFF_XB;  // overlay: xb/W1t dead after gemm1n

  unsigned short* xb  = (unsigned short*)(ws + OFF_XB);
  unsigned short* W1t = (unsigned short*)(ws + OFF_W1T);
  unsigned short* W2t = (unsigned short*)(ws + OFF_W2T);
  unsigned short* h   = (unsigned short*)(ws + OFF_H);

  k_router<<<NTOK / 4, 256, 0, stream>>>(x, Wr, br, probs, idxf, idxi, xb);
  k_compact<<<1, 512, 0, stream>>>(idxi, cnt, off, sorted, meta);
  k_trcvt64<<<dim3(HH / 64, DD / 64, EE), 256, 0, stream>>>(W1, W1t, DD, HH);
  k_gemm1n<<<dim3(MAXBLK, HH / 128), 256, 0, stream>>>(xb, W1t, b1, meta, cnt, off, sorted, h);
  k_trcvt64<<<dim3(DD / 64, HH / 64, EE), 256, 0, stream>>>(W2, W2t, HH, DD);
  k_gemm2n<<<dim3(MAXBLK, DD / 128), 256, 0, stream>>>(h, W2t, b2, meta, cnt, off, sorted, out);
}

// Round 4
// 400.256 us; speedup vs baseline: 1.0294x; 1.0294x over previous
//
#include <hip/hip_runtime.h>

#define NTOK 8192
#define DD 1024
#define HH 4096
#define EE 8
#define MAXBLK 72

typedef __attribute__((ext_vector_type(8))) short bf16x8;
typedef __attribute__((ext_vector_type(4))) float f32x4;

__device__ __forceinline__ unsigned short f2bf(float f) {
  unsigned u = __builtin_bit_cast(unsigned, f);
  u += 0x7fffu + ((u >> 16) & 1u);  // round-to-nearest-even
  return (unsigned short)(u >> 16);
}

union Pack8 {
  unsigned short u[8];
  uint4 v;
};

__device__ __forceinline__ void gload_lds16(const void* g, void* l) {
  __builtin_amdgcn_global_load_lds(
      (const __attribute__((address_space(1))) unsigned int*)g,
      (__attribute__((address_space(3))) unsigned int*)l, 16, 0, 0);
}

// ---------------- Router (fused x -> bf16 convert) ----------------
__global__ __launch_bounds__(256) void k_router(
    const float* __restrict__ x, const float* __restrict__ Wr,
    const float* __restrict__ br, float* __restrict__ probs,
    float* __restrict__ idxf, int* __restrict__ idxi,
    unsigned short* __restrict__ xb) {
  const int lane = threadIdx.x & 63;
  const int token = blockIdx.x * 4 + (threadIdx.x >> 6);
  const float* xr = x + (size_t)token * DD;

  float acc[EE];
#pragma unroll
  for (int e = 0; e < EE; ++e) acc[e] = 0.f;

#pragma unroll
  for (int i = 0; i < 4; ++i) {
    const int d0 = i * 256 + lane * 4;
    const float4 xv = *reinterpret_cast<const float4*>(xr + d0);
    union { unsigned short u[4]; uint2 v; } pk;
    pk.u[0] = f2bf(xv.x); pk.u[1] = f2bf(xv.y);
    pk.u[2] = f2bf(xv.z); pk.u[3] = f2bf(xv.w);
    *reinterpret_cast<uint2*>(xb + (size_t)token * DD + d0) = pk.v;
    const float xs[4] = {xv.x, xv.y, xv.z, xv.w};
#pragma unroll
    for (int j = 0; j < 4; ++j) {
      const float xd = xs[j];
      const float4 w0 = *reinterpret_cast<const float4*>(Wr + (size_t)(d0 + j) * EE);
      const float4 w1 = *reinterpret_cast<const float4*>(Wr + (size_t)(d0 + j) * EE + 4);
      acc[0] += xd * w0.x; acc[1] += xd * w0.y; acc[2] += xd * w0.z; acc[3] += xd * w0.w;
      acc[4] += xd * w1.x; acc[5] += xd * w1.y; acc[6] += xd * w1.z; acc[7] += xd * w1.w;
    }
  }
#pragma unroll
  for (int s = 32; s > 0; s >>= 1) {
#pragma unroll
    for (int e = 0; e < EE; ++e) acc[e] += __shfl_xor(acc[e], s, 64);
  }

  float lg[EE];
#pragma unroll
  for (int e = 0; e < EE; ++e) lg[e] = acc[e] + br[e];

  int best = 0;
  float bv = lg[0];
#pragma unroll
  for (int e = 1; e < EE; ++e) {
    if (lg[e] > bv) { bv = lg[e]; best = e; }  // strict > = numpy first-max
  }
  float p[EE], s = 0.f;
#pragma unroll
  for (int e = 0; e < EE; ++e) { p[e] = expf(lg[e] - bv); s += p[e]; }
  const float inv = 1.f / s;

  if (lane == 0) {
#pragma unroll
    for (int e = 0; e < EE; ++e) probs[(size_t)token * EE + e] = p[e] * inv;
    idxf[token] = (float)best;
    idxi[token] = best;
  }
}

// ------------- Stable compaction + block table -------------
__global__ __launch_bounds__(512) void k_compact(const int* __restrict__ idxi,
                                                 int* __restrict__ cnt,
                                                 int* __restrict__ off,
                                                 int* __restrict__ sorted,
                                                 int* __restrict__ meta) {
  __shared__ int sidx[NTOK];
  __shared__ int scnt[EE], soff[EE];
  const int tid = threadIdx.x;
  for (int i = tid; i < NTOK; i += 512) sidx[i] = idxi[i];
  __syncthreads();
  const int w = tid >> 6, lane = tid & 63;
  if (w < EE) {
    int c = 0;
    for (int i = 0; i < NTOK / 64; ++i) {
      unsigned long long m = __ballot(sidx[i * 64 + lane] == w);
      c += __popcll(m);
    }
    if (lane == 0) scnt[w] = c;
  }
  __syncthreads();
  if (tid == 0) {
    int s = 0;
    for (int e = 0; e < EE; ++e) { soff[e] = s; s += scnt[e]; }
    int nb = 0;
    for (int e = 0; e < EE; ++e) {
      const int nmb = (scnt[e] + 127) >> 7;
      for (int m = 0; m < nmb; ++m) {
        meta[16 + nb] = e;
        meta[96 + nb] = m << 7;
        ++nb;
      }
    }
    meta[0] = nb;
  }
  __syncthreads();
  if (w < EE) {
    int base = soff[w];
    const unsigned long long ltmask = (1ull << lane) - 1ull;
    for (int i = 0; i < NTOK / 64; ++i) {
      const int tok = i * 64 + lane;
      const bool f = (sidx[tok] == w);
      unsigned long long m = __ballot(f);
      if (f) {
        int r = __popcll(m & ltmask);
        sorted[base + r] = tok;
      }
      base += __popcll(m);
    }
    if (lane == 0) { cnt[w] = scnt[w]; off[w] = soff[w]; }
  }
}

// ---------------- transpose+convert 64x64: in [E][R][C] f32 -> out [E][C][R] bf16 ----------------
__global__ __launch_bounds__(256) void k_trcvt64(const float* __restrict__ in,
                                                 unsigned short* __restrict__ outp,
                                                 int R, int C) {
  const int e = blockIdx.z;
  const int r0 = blockIdx.y * 64, c0 = blockIdx.x * 64;
  const float* src = in + (size_t)e * R * C + (size_t)r0 * C + c0;
  unsigned short* dst = outp + (size_t)e * R * C + (size_t)c0 * R + r0;
  __shared__ unsigned short t[64 * 66];
  const int tid = threadIdx.x;
#pragma unroll
  for (int it = 0; it < 4; ++it) {
    const int r = it * 16 + (tid >> 4), c4 = (tid & 15) * 4;
    const float4 v = *reinterpret_cast<const float4*>(src + (size_t)r * C + c4);
    t[r * 66 + c4 + 0] = f2bf(v.x);
    t[r * 66 + c4 + 1] = f2bf(v.y);
    t[r * 66 + c4 + 2] = f2bf(v.z);
    t[r * 66 + c4 + 3] = f2bf(v.w);
  }
  __syncthreads();
#pragma unroll
  for (int it = 0; it < 2; ++it) {
    const int cc = it * 32 + (tid >> 3), r8 = (tid & 7) * 8;
    Pack8 p;
#pragma unroll
    for (int j = 0; j < 8; ++j) p.u[j] = t[(r8 + j) * 66 + cc];
    *reinterpret_cast<uint4*>(dst + (size_t)cc * R + r8) = p.v;
  }
}

// ---------------- GEMM1: h = relu(xb_sel @ W1t^T + b1) -> bf16 (round-2 structure) ----------------
__global__ __launch_bounds__(256) void k_gemm1n(
    const unsigned short* __restrict__ xb, const unsigned short* __restrict__ W1t,
    const float* __restrict__ b1, const int* __restrict__ meta,
    const int* __restrict__ cnt, const int* __restrict__ off,
    const int* __restrict__ sorted, unsigned short* __restrict__ h) {
  const int bid = blockIdx.x;
  if (bid >= meta[0]) return;
  const int e = meta[16 + bid];
  const int m0 = meta[96 + bid];
  const int c = cnt[e], base = off[e];
  const int n0 = blockIdx.y * 128;

  __shared__ __align__(16) unsigned short Al[128 * 64];
  __shared__ __align__(16) unsigned short Bl[128 * 64];

  const int tid = threadIdx.x, l = tid & 63, w = tid >> 6;

  const unsigned short* aptr[4];
  const unsigned short* bptr[4];
  int soff4[4];
#pragma unroll
  for (int i = 0; i < 4; ++i) {
    const int r = i * 32 + w * 8 + (l >> 3);
    const int swz = ((l & 7) ^ (r & 7)) * 8;  // pre-swizzled global source
    int ar = m0 + r; if (ar >= c) ar = c - 1;
    const int tok = sorted[base + ar];
    aptr[i] = xb + (size_t)tok * DD + swz;
    bptr[i] = W1t + ((size_t)e * HH + n0 + r) * DD + swz;
    soff4[i] = r * 64 + (l & 7) * 8;
  }

  const int lr = l & 15, lg = l >> 4;
  const int wr = w >> 1, wc = w & 1;
  int aoff[4], boff[4], asw[4], bsw[4];
#pragma unroll
  for (int m = 0; m < 4; ++m) {
    int row = wr * 64 + m * 16 + lr;
    aoff[m] = row * 64; asw[m] = row & 7;
    row = wc * 64 + m * 16 + lr;
    boff[m] = row * 64; bsw[m] = row & 7;
  }

  f32x4 acc[4][4];
#pragma unroll
  for (int m = 0; m < 4; ++m)
#pragma unroll
    for (int n = 0; n < 4; ++n) acc[m][n] = {0.f, 0.f, 0.f, 0.f};

  for (int k0 = 0; k0 < DD; k0 += 64) {
    __syncthreads();
#pragma unroll
    for (int i = 0; i < 4; ++i) gload_lds16(aptr[i] + k0, &Al[soff4[i]]);
#pragma unroll
    for (int i = 0; i < 4; ++i) gload_lds16(bptr[i] + k0, &Bl[soff4[i]]);
    __syncthreads();
#pragma unroll
    for (int ks = 0; ks < 2; ++ks) {
      bf16x8 af[4], bv[4];
#pragma unroll
      for (int m = 0; m < 4; ++m)
        af[m] = *reinterpret_cast<const bf16x8*>(&Al[aoff[m] + (((ks * 4 + lg) ^ asw[m]) * 8)]);
#pragma unroll
      for (int n = 0; n < 4; ++n)
        bv[n] = *reinterpret_cast<const bf16x8*>(&Bl[boff[n] + (((ks * 4 + lg) ^ bsw[n]) * 8)]);
#pragma unroll
      for (int m = 0; m < 4; ++m)
#pragma unroll
        for (int n = 0; n < 4; ++n)
          acc[m][n] = __builtin_amdgcn_mfma_f32_16x16x32_bf16(af[m], bv[n], acc[m][n], 0, 0, 0);
    }
  }

  const int valid = c - m0;
#pragma unroll
  for (int m = 0; m < 4; ++m) {
#pragma unroll
    for (int rr = 0; rr < 4; ++rr) {
      const int tr = wr * 64 + m * 16 + lg * 4 + rr;
      if (tr < valid) {
        const size_t row = (size_t)(base + m0 + tr);
#pragma unroll
        for (int n = 0; n < 4; ++n) {
          const int col = n0 + wc * 64 + n * 16 + lr;
          const float v = acc[m][n][rr] + b1[e * HH + col];
          h[row * HH + col] = f2bf(fmaxf(v, 0.f));
        }
      }
    }
  }
}

// ---------------- GEMM2: 512-thread, in-block split-K over 2 wave groups ----------------
// Group g handles K-half [g*2048, (g+1)*2048). Group 1's partial is reduced via LDS.
__global__ __launch_bounds__(512) void k_gemm2s(
    const unsigned short* __restrict__ h, const unsigned short* __restrict__ W2t,
    const float* __restrict__ b2, const int* __restrict__ meta,
    const int* __restrict__ cnt, const int* __restrict__ off,
    const int* __restrict__ sorted, float* __restrict__ out) {
  const int bid = blockIdx.x;
  if (bid >= meta[0]) return;
  const int e = meta[16 + bid];
  const int m0 = meta[96 + bid];
  const int c = cnt[e], base = off[e];
  const int n0 = blockIdx.y * 128;

  // [0..1] = A per group, [2..3] = B per group; 64 KB total. Reused as f32[128][128] for reduce.
  __shared__ __align__(16) unsigned short LDSU[4][128 * 64];

  const int tid = threadIdx.x, l = tid & 63;
  const int w = tid >> 6;          // 0..7
  const int g = w >> 2;            // K-half group
  const int wg = w & 3;            // wave within group

  const unsigned short* aptr[4];
  const unsigned short* bptr[4];
  int soff4[4];
#pragma unroll
  for (int i = 0; i < 4; ++i) {
    const int r = i * 32 + wg * 8 + (l >> 3);
    const int swz = ((l & 7) ^ (r & 7)) * 8;
    int ar = m0 + r; if (ar >= c) ar = c - 1;
    aptr[i] = h + (size_t)(base + ar) * HH + g * 2048 + swz;
    bptr[i] = W2t + ((size_t)e * DD + n0 + r) * HH + g * 2048 + swz;
    soff4[i] = r * 64 + (l & 7) * 8;
  }

  const int lr = l & 15, lg = l >> 4;
  const int wr = wg >> 1, wc = wg & 1;
  int aoff[4], boff[4], asw[4], bsw[4];
#pragma unroll
  for (int m = 0; m < 4; ++m) {
    int row = wr * 64 + m * 16 + lr;
    aoff[m] = row * 64; asw[m] = row & 7;
    row = wc * 64 + m * 16 + lr;
    boff[m] = row * 64; bsw[m] = row & 7;
  }

  f32x4 acc[4][4];
#pragma unroll
  for (int m = 0; m < 4; ++m)
#pragma unroll
    for (int n = 0; n < 4; ++n) acc[m][n] = {0.f, 0.f, 0.f, 0.f};

  for (int t = 0; t < 32; ++t) {
    const int k0 = t * 64;
    __syncthreads();
#pragma unroll
    for (int i = 0; i < 4; ++i) gload_lds16(aptr[i] + k0, &LDSU[g][soff4[i]]);
#pragma unroll
    for (int i = 0; i < 4; ++i) gload_lds16(bptr[i] + k0, &LDSU[2 + g][soff4[i]]);
    __syncthreads();
#pragma unroll
    for (int ks = 0; ks < 2; ++ks) {
      bf16x8 af[4], bv[4];
#pragma unroll
      for (int m = 0; m < 4; ++m)
        af[m] = *reinterpret_cast<const bf16x8*>(&LDSU[g][aoff[m] + (((ks * 4 + lg) ^ asw[m]) * 8)]);
#pragma unroll
      for (int n = 0; n < 4; ++n)
        bv[n] = *reinterpret_cast<const bf16x8*>(&LDSU[2 + g][boff[n] + (((ks * 4 + lg) ^ bsw[n]) * 8)]);
#pragma unroll
      for (int m = 0; m < 4; ++m)
#pragma unroll
        for (int n = 0; n < 4; ++n)
          acc[m][n] = __builtin_amdgcn_mfma_f32_16x16x32_bf16(af[m], bv[n], acc[m][n], 0, 0, 0);
    }
  }

  // ---- split-K reduce via LDS (deterministic 2-addend sum) ----
  __syncthreads();
  float* red = (float*)LDSU;  // 64 KB = 128x128 f32
  if (g == 1) {
#pragma unroll
    for (int m = 0; m < 4; ++m)
#pragma unroll
      for (int rr = 0; rr < 4; ++rr) {
        const int row = wr * 64 + m * 16 + lg * 4 + rr;
#pragma unroll
        for (int n = 0; n < 4; ++n) {
          const int col = wc * 64 + n * 16 + lr;
          red[row * 128 + col] = acc[m][n][rr];
        }
      }
  }
  __syncthreads();
  if (g == 0) {
    const int valid = c - m0;
#pragma unroll
    for (int m = 0; m < 4; ++m) {
#pragma unroll
      for (int rr = 0; rr < 4; ++rr) {
        const int tr = wr * 64 + m * 16 + lg * 4 + rr;
        if (tr < valid) {
          const int token = sorted[base + m0 + tr];
#pragma unroll
          for (int n = 0; n < 4; ++n) {
            const int col = wc * 64 + n * 16 + lr;
            out[(size_t)token * DD + n0 + col] =
                acc[m][n][rr] + red[tr * 128 + col] + b2[e * DD + n0 + col];
          }
        }
      }
    }
  }
}

extern "C" void kernel_launch(void* const* d_in, const int* in_sizes, int n_in,
                              void* d_out, int out_size, void* d_ws, size_t ws_size,
                              hipStream_t stream) {
  const float* x  = (const float*)d_in[0];
  const float* Wr = (const float*)d_in[1];
  const float* br = (const float*)d_in[2];
  const float* W1 = (const float*)d_in[3];
  const float* b1 = (const float*)d_in[4];
  const float* W2 = (const float*)d_in[5];
  const float* b2 = (const float*)d_in[6];

  float* out   = (float*)d_out;
  float* probs = out + (size_t)NTOK * DD;
  float* idxf  = probs + (size_t)NTOK * EE;

  char* ws = (char*)d_ws;
  int* cnt    = (int*)(ws + 0);
  int* off    = (int*)(ws + 64);
  int* meta   = (int*)(ws + 128);      // [0]=nblk, [16..]=blk_e, [96..]=blk_m0
  int* idxi   = (int*)(ws + 1024);
  int* sorted = (int*)(ws + 33792);

  const size_t OFF_XB  = 66560;                                  // 16 MB
  const size_t OFF_W1T = OFF_XB + (size_t)NTOK * DD * 2;         // +64 MB
  const size_t OFF_H   = OFF_W1T + (size_t)EE * DD * HH * 2;     // +64 MB
  const size_t OFF_W2T = OFF_XB;  // overlay: xb/W1t dead after gemm1n

  unsigned short* xb  = (unsigned short*)(ws + OFF_XB);
  unsigned short* W1t = (unsigned short*)(ws + OFF_W1T);
  unsigned short* W2t = (unsigned short*)(ws + OFF_W2T);
  unsigned short* h   = (unsigned short*)(ws + OFF_H);

  k_router<<<NTOK / 4, 256, 0, stream>>>(x, Wr, br, probs, idxf, idxi, xb);
  k_compact<<<1, 512, 0, stream>>>(idxi, cnt, off, sorted, meta);
  k_trcvt64<<<dim3(HH / 64, DD / 64, EE), 256, 0, stream>>>(W1, W1t, DD, HH);
  k_gemm1n<<<dim3(MAXBLK, HH / 128), 256, 0, stream>>>(xb, W1t, b1, meta, cnt, off, sorted, h);
  k_trcvt64<<<dim3(DD / 64, HH / 64, EE), 256, 0, stream>>>(W2, W2t, HH, DD);
  k_gemm2s<<<dim3(MAXBLK, DD / 128), 512, 0, stream>>>(h, W2t, b2, meta, cnt, off, sorted, out);
}

// Round 5
// 374.963 us; speedup vs baseline: 1.0989x; 1.0675x over previous
//
#include <hip/hip_runtime.h>

#define NTOK 8192
#define DD 1024
#define HH 4096
#define EE 8
#define MAXBLK 72

typedef __attribute__((ext_vector_type(8))) short bf16x8;
typedef __attribute__((ext_vector_type(4))) float f32x4;

__device__ __forceinline__ unsigned short f2bf(float f) {
  unsigned u = __builtin_bit_cast(unsigned, f);
  u += 0x7fffu + ((u >> 16) & 1u);  // round-to-nearest-even
  return (unsigned short)(u >> 16);
}

union Pack8 {
  unsigned short u[8];
  uint4 v;
};

__device__ __forceinline__ void gload_lds16(const void* g, void* l) {
  __builtin_amdgcn_global_load_lds(
      (const __attribute__((address_space(1))) unsigned int*)g,
      (__attribute__((address_space(3))) unsigned int*)l, 16, 0, 0);
}

// ---------------- Router (fused x -> bf16 convert) ----------------
__global__ __launch_bounds__(256) void k_router(
    const float* __restrict__ x, const float* __restrict__ Wr,
    const float* __restrict__ br, float* __restrict__ probs,
    float* __restrict__ idxf, int* __restrict__ idxi,
    unsigned short* __restrict__ xb) {
  const int lane = threadIdx.x & 63;
  const int token = blockIdx.x * 4 + (threadIdx.x >> 6);
  const float* xr = x + (size_t)token * DD;

  float acc[EE];
#pragma unroll
  for (int e = 0; e < EE; ++e) acc[e] = 0.f;

#pragma unroll
  for (int i = 0; i < 4; ++i) {
    const int d0 = i * 256 + lane * 4;
    const float4 xv = *reinterpret_cast<const float4*>(xr + d0);
    union { unsigned short u[4]; uint2 v; } pk;
    pk.u[0] = f2bf(xv.x); pk.u[1] = f2bf(xv.y);
    pk.u[2] = f2bf(xv.z); pk.u[3] = f2bf(xv.w);
    *reinterpret_cast<uint2*>(xb + (size_t)token * DD + d0) = pk.v;
    const float xs[4] = {xv.x, xv.y, xv.z, xv.w};
#pragma unroll
    for (int j = 0; j < 4; ++j) {
      const float xd = xs[j];
      const float4 w0 = *reinterpret_cast<const float4*>(Wr + (size_t)(d0 + j) * EE);
      const float4 w1 = *reinterpret_cast<const float4*>(Wr + (size_t)(d0 + j) * EE + 4);
      acc[0] += xd * w0.x; acc[1] += xd * w0.y; acc[2] += xd * w0.z; acc[3] += xd * w0.w;
      acc[4] += xd * w1.x; acc[5] += xd * w1.y; acc[6] += xd * w1.z; acc[7] += xd * w1.w;
    }
  }
#pragma unroll
  for (int s = 32; s > 0; s >>= 1) {
#pragma unroll
    for (int e = 0; e < EE; ++e) acc[e] += __shfl_xor(acc[e], s, 64);
  }

  float lg[EE];
#pragma unroll
  for (int e = 0; e < EE; ++e) lg[e] = acc[e] + br[e];

  int best = 0;
  float bv = lg[0];
#pragma unroll
  for (int e = 1; e < EE; ++e) {
    if (lg[e] > bv) { bv = lg[e]; best = e; }  // strict > = numpy first-max
  }
  float p[EE], s = 0.f;
#pragma unroll
  for (int e = 0; e < EE; ++e) { p[e] = expf(lg[e] - bv); s += p[e]; }
  const float inv = 1.f / s;

  if (lane == 0) {
#pragma unroll
    for (int e = 0; e < EE; ++e) probs[(size_t)token * EE + e] = p[e] * inv;
    idxf[token] = (float)best;
    idxi[token] = best;
  }
}

// ------------- Stable compaction + block table -------------
__global__ __launch_bounds__(512) void k_compact(const int* __restrict__ idxi,
                                                 int* __restrict__ cnt,
                                                 int* __restrict__ off,
                                                 int* __restrict__ sorted,
                                                 int* __restrict__ meta) {
  __shared__ int sidx[NTOK];
  __shared__ int scnt[EE], soff[EE];
  const int tid = threadIdx.x;
  for (int i = tid; i < NTOK; i += 512) sidx[i] = idxi[i];
  __syncthreads();
  const int w = tid >> 6, lane = tid & 63;
  if (w < EE) {
    int c = 0;
    for (int i = 0; i < NTOK / 64; ++i) {
      unsigned long long m = __ballot(sidx[i * 64 + lane] == w);
      c += __popcll(m);
    }
    if (lane == 0) scnt[w] = c;
  }
  __syncthreads();
  if (tid == 0) {
    int s = 0;
    for (int e = 0; e < EE; ++e) { soff[e] = s; s += scnt[e]; }
    int nb = 0;
    for (int e = 0; e < EE; ++e) {
      const int nmb = (scnt[e] + 127) >> 7;
      for (int m = 0; m < nmb; ++m) {
        meta[16 + nb] = e;
        meta[96 + nb] = m << 7;
        ++nb;
      }
    }
    meta[0] = nb;
  }
  __syncthreads();
  if (w < EE) {
    int base = soff[w];
    const unsigned long long ltmask = (1ull << lane) - 1ull;
    for (int i = 0; i < NTOK / 64; ++i) {
      const int tok = i * 64 + lane;
      const bool f = (sidx[tok] == w);
      unsigned long long m = __ballot(f);
      if (f) {
        int r = __popcll(m & ltmask);
        sorted[base + r] = tok;
      }
      base += __popcll(m);
    }
    if (lane == 0) { cnt[w] = scnt[w]; off[w] = soff[w]; }
  }
}

// ---------------- transpose+convert 64x64: in [E][R][C] f32 -> out [E][C][R] bf16 ----------------
__global__ __launch_bounds__(256) void k_trcvt64(const float* __restrict__ in,
                                                 unsigned short* __restrict__ outp,
                                                 int R, int C) {
  const int e = blockIdx.z;
  const int r0 = blockIdx.y * 64, c0 = blockIdx.x * 64;
  const float* src = in + (size_t)e * R * C + (size_t)r0 * C + c0;
  unsigned short* dst = outp + (size_t)e * R * C + (size_t)c0 * R + r0;
  __shared__ unsigned short t[64 * 66];
  const int tid = threadIdx.x;
#pragma unroll
  for (int it = 0; it < 4; ++it) {
    const int r = it * 16 + (tid >> 4), c4 = (tid & 15) * 4;
    const float4 v = *reinterpret_cast<const float4*>(src + (size_t)r * C + c4);
    t[r * 66 + c4 + 0] = f2bf(v.x);
    t[r * 66 + c4 + 1] = f2bf(v.y);
    t[r * 66 + c4 + 2] = f2bf(v.z);
    t[r * 66 + c4 + 3] = f2bf(v.w);
  }
  __syncthreads();
#pragma unroll
  for (int it = 0; it < 2; ++it) {
    const int cc = it * 32 + (tid >> 3), r8 = (tid & 7) * 8;
    Pack8 p;
#pragma unroll
    for (int j = 0; j < 8; ++j) p.u[j] = t[(r8 + j) * 66 + cc];
    *reinterpret_cast<uint4*>(dst + (size_t)cc * R + r8) = p.v;
  }
}

// ---------------- GEMM1: h = relu(xb_sel @ W1t^T + b1) -> bf16 ----------------
// grid = (HH/128, MAXBLK): x = N-block (consecutive blocks share the A panel)
__global__ __launch_bounds__(256) void k_gemm1n(
    const unsigned short* __restrict__ xb, const unsigned short* __restrict__ W1t,
    const float* __restrict__ b1, const int* __restrict__ meta,
    const int* __restrict__ cnt, const int* __restrict__ off,
    const int* __restrict__ sorted, unsigned short* __restrict__ h) {
  const int bid = blockIdx.y;
  if (bid >= meta[0]) return;
  const int e = meta[16 + bid];
  const int m0 = meta[96 + bid];
  const int c = cnt[e], base = off[e];
  const int n0 = blockIdx.x * 128;

  __shared__ __align__(16) unsigned short Al[128 * 64];
  __shared__ __align__(16) unsigned short Bl[128 * 64];

  const int tid = threadIdx.x, l = tid & 63, w = tid >> 6;

  const unsigned short* aptr[4];
  const unsigned short* bptr[4];
  int soff4[4];
#pragma unroll
  for (int i = 0; i < 4; ++i) {
    const int r = i * 32 + w * 8 + (l >> 3);
    const int swz = ((l & 7) ^ (r & 7)) * 8;  // pre-swizzled global source
    int ar = m0 + r; if (ar >= c) ar = c - 1;
    const int tok = sorted[base + ar];
    aptr[i] = xb + (size_t)tok * DD + swz;
    bptr[i] = W1t + ((size_t)e * HH + n0 + r) * DD + swz;
    soff4[i] = r * 64 + (l & 7) * 8;
  }

  const int lr = l & 15, lg = l >> 4;
  const int wr = w >> 1, wc = w & 1;
  int aoff[4], boff[4], asw[4], bsw[4];
#pragma unroll
  for (int m = 0; m < 4; ++m) {
    int row = wr * 64 + m * 16 + lr;
    aoff[m] = row * 64; asw[m] = row & 7;
    row = wc * 64 + m * 16 + lr;
    boff[m] = row * 64; bsw[m] = row & 7;
  }

  f32x4 acc[4][4];
#pragma unroll
  for (int m = 0; m < 4; ++m)
#pragma unroll
    for (int n = 0; n < 4; ++n) acc[m][n] = {0.f, 0.f, 0.f, 0.f};

  for (int k0 = 0; k0 < DD; k0 += 64) {
    __syncthreads();
#pragma unroll
    for (int i = 0; i < 4; ++i) gload_lds16(aptr[i] + k0, &Al[soff4[i]]);
#pragma unroll
    for (int i = 0; i < 4; ++i) gload_lds16(bptr[i] + k0, &Bl[soff4[i]]);
    __syncthreads();
#pragma unroll
    for (int ks = 0; ks < 2; ++ks) {
      bf16x8 af[4], bv[4];
#pragma unroll
      for (int m = 0; m < 4; ++m)
        af[m] = *reinterpret_cast<const bf16x8*>(&Al[aoff[m] + (((ks * 4 + lg) ^ asw[m]) * 8)]);
#pragma unroll
      for (int n = 0; n < 4; ++n)
        bv[n] = *reinterpret_cast<const bf16x8*>(&Bl[boff[n] + (((ks * 4 + lg) ^ bsw[n]) * 8)]);
#pragma unroll
      for (int m = 0; m < 4; ++m)
#pragma unroll
        for (int n = 0; n < 4; ++n)
          acc[m][n] = __builtin_amdgcn_mfma_f32_16x16x32_bf16(af[m], bv[n], acc[m][n], 0, 0, 0);
    }
  }

  const int valid = c - m0;
#pragma unroll
  for (int m = 0; m < 4; ++m) {
#pragma unroll
    for (int rr = 0; rr < 4; ++rr) {
      const int tr = wr * 64 + m * 16 + lg * 4 + rr;
      if (tr < valid) {
        const size_t row = (size_t)(base + m0 + tr);
#pragma unroll
        for (int n = 0; n < 4; ++n) {
          const int col = n0 + wc * 64 + n * 16 + lr;
          const float v = acc[m][n][rr] + b1[e * HH + col];
          h[row * HH + col] = f2bf(fmaxf(v, 0.f));
        }
      }
    }
  }
}

// ---------------- GEMM2: out = h @ W2t^T + b2, BM=128 BN=64 (TLP: 1152 blocks) ----------------
// grid = (DD/64, MAXBLK): x = N-block (16 consecutive blocks share one A panel)
__global__ __launch_bounds__(256) void k_gemm2w(
    const unsigned short* __restrict__ h, const unsigned short* __restrict__ W2t,
    const float* __restrict__ b2, const int* __restrict__ meta,
    const int* __restrict__ cnt, const int* __restrict__ off,
    const int* __restrict__ sorted, float* __restrict__ out) {
  const int bid = blockIdx.y;
  if (bid >= meta[0]) return;
  const int e = meta[16 + bid];
  const int m0 = meta[96 + bid];
  const int c = cnt[e], base = off[e];
  const int n0 = blockIdx.x * 64;

  __shared__ __align__(16) unsigned short Al[128 * 64];
  __shared__ __align__(16) unsigned short Bl[64 * 64];

  const int tid = threadIdx.x, l = tid & 63, w = tid >> 6;

  const unsigned short* aptr[4];
  const unsigned short* bptr[2];
  int asoff[4], bsoff[2];
#pragma unroll
  for (int i = 0; i < 4; ++i) {
    const int r = i * 32 + w * 8 + (l >> 3);
    const int swz = ((l & 7) ^ (r & 7)) * 8;
    int ar = m0 + r; if (ar >= c) ar = c - 1;
    aptr[i] = h + (size_t)(base + ar) * HH + swz;
    asoff[i] = r * 64 + (l & 7) * 8;
  }
#pragma unroll
  for (int i = 0; i < 2; ++i) {
    const int r = i * 32 + w * 8 + (l >> 3);
    const int swz = ((l & 7) ^ (r & 7)) * 8;
    bptr[i] = W2t + ((size_t)e * DD + n0 + r) * HH + swz;
    bsoff[i] = r * 64 + (l & 7) * 8;
  }

  const int lr = l & 15, lg = l >> 4;
  const int wr = w >> 1, wc = w & 1;   // M in 64-halves, N in 32-halves
  int aoff[4], boff[2], asw[4], bsw[2];
#pragma unroll
  for (int m = 0; m < 4; ++m) {
    const int row = wr * 64 + m * 16 + lr;
    aoff[m] = row * 64; asw[m] = row & 7;
  }
#pragma unroll
  for (int n = 0; n < 2; ++n) {
    const int row = wc * 32 + n * 16 + lr;
    boff[n] = row * 64; bsw[n] = row & 7;
  }

  f32x4 acc[4][2];
#pragma unroll
  for (int m = 0; m < 4; ++m)
#pragma unroll
    for (int n = 0; n < 2; ++n) acc[m][n] = {0.f, 0.f, 0.f, 0.f};

  for (int k0 = 0; k0 < HH; k0 += 64) {
    __syncthreads();
#pragma unroll
    for (int i = 0; i < 4; ++i) gload_lds16(aptr[i] + k0, &Al[asoff[i]]);
#pragma unroll
    for (int i = 0; i < 2; ++i) gload_lds16(bptr[i] + k0, &Bl[bsoff[i]]);
    __syncthreads();
#pragma unroll
    for (int ks = 0; ks < 2; ++ks) {
      bf16x8 af[4], bv[2];
#pragma unroll
      for (int m = 0; m < 4; ++m)
        af[m] = *reinterpret_cast<const bf16x8*>(&Al[aoff[m] + (((ks * 4 + lg) ^ asw[m]) * 8)]);
#pragma unroll
      for (int n = 0; n < 2; ++n)
        bv[n] = *reinterpret_cast<const bf16x8*>(&Bl[boff[n] + (((ks * 4 + lg) ^ bsw[n]) * 8)]);
#pragma unroll
      for (int m = 0; m < 4; ++m)
#pragma unroll
        for (int n = 0; n < 2; ++n)
          acc[m][n] = __builtin_amdgcn_mfma_f32_16x16x32_bf16(af[m], bv[n], acc[m][n], 0, 0, 0);
    }
  }

  const int valid = c - m0;
#pragma unroll
  for (int m = 0; m < 4; ++m) {
#pragma unroll
    for (int rr = 0; rr < 4; ++rr) {
      const int tr = wr * 64 + m * 16 + lg * 4 + rr;
      if (tr < valid) {
        const int token = sorted[base + m0 + tr];
#pragma unroll
        for (int n = 0; n < 2; ++n) {
          const int col = n0 + wc * 32 + n * 16 + lr;
          out[(size_t)token * DD + col] = acc[m][n][rr] + b2[e * DD + col];
        }
      }
    }
  }
}

extern "C" void kernel_launch(void* const* d_in, const int* in_sizes, int n_in,
                              void* d_out, int out_size, void* d_ws, size_t ws_size,
                              hipStream_t stream) {
  const float* x  = (const float*)d_in[0];
  const float* Wr = (const float*)d_in[1];
  const float* br = (const float*)d_in[2];
  const float* W1 = (const float*)d_in[3];
  const float* b1 = (const float*)d_in[4];
  const float* W2 = (const float*)d_in[5];
  const float* b2 = (const float*)d_in[6];

  float* out   = (float*)d_out;
  float* probs = out + (size_t)NTOK * DD;
  float* idxf  = probs + (size_t)NTOK * EE;

  char* ws = (char*)d_ws;
  int* cnt    = (int*)(ws + 0);
  int* off    = (int*)(ws + 64);
  int* meta   = (int*)(ws + 128);      // [0]=nblk, [16..]=blk_e, [96..]=blk_m0
  int* idxi   = (int*)(ws + 1024);
  int* sorted = (int*)(ws + 33792);

  const size_t OFF_XB  = 66560;                                  // 16 MB
  const size_t OFF_W1T = OFF_XB + (size_t)NTOK * DD * 2;         // +64 MB
  const size_t OFF_H   = OFF_W1T + (size_t)EE * DD * HH * 2;     // +64 MB
  const size_t OFF_W2T = OFF_XB;  // overlay: xb/W1t dead after gemm1n

  unsigned short* xb  = (unsigned short*)(ws + OFF_XB);
  unsigned short* W1t = (unsigned short*)(ws + OFF_W1T);
  unsigned short* W2t = (unsigned short*)(ws + OFF_W2T);
  unsigned short* h   = (unsigned short*)(ws + OFF_H);

  k_router<<<NTOK / 4, 256, 0, stream>>>(x, Wr, br, probs, idxf, idxi, xb);
  k_compact<<<1, 512, 0, stream>>>(idxi, cnt, off, sorted, meta);
  k_trcvt64<<<dim3(HH / 64, DD / 64, EE), 256, 0, stream>>>(W1, W1t, DD, HH);
  k_gemm1n<<<dim3(HH / 128, MAXBLK), 256, 0, stream>>>(xb, W1t, b1, meta, cnt, off, sorted, h);
  k_trcvt64<<<dim3(DD / 64, HH / 64, EE), 256, 0, stream>>>(W2, W2t, HH, DD);
  k_gemm2w<<<dim3(DD / 64, MAXBLK), 256, 0, stream>>>(h, W2t, b2, meta, cnt, off, sorted, out);
}